// Round 2
// baseline (404.477 us; speedup 1.0000x reference)
//
#include <hip/hip_runtime.h>
#include <hip/hip_bf16.h>
#include <cstdint>
#include <cstddef>

typedef __bf16 bf16;
typedef __attribute__((ext_vector_type(8))) __bf16 bf16x8;
typedef __attribute__((ext_vector_type(4))) __bf16 bf16x4;
typedef __attribute__((ext_vector_type(4))) float f32x4;

#define MFMA_BF16(a, b, c) __builtin_amdgcn_mfma_f32_16x16x32_bf16((a), (b), (c), 0, 0, 0)

constexpr int CB = 4;       // batch
constexpr int CS = 2048;    // seq
constexpr int CD = 1024;    // model dim
constexpr int CDA = 1024;   // attn dim
constexpr int CH = 16;      // heads
constexpr int CDH = 64;     // per-head dim
constexpr int CM = CB * CS; // 8192 rows

// ---------------------------------------------------------------------------
// GEMM: C[M,N] = A[M,K] * W[N,K]^T + bias[N]
// A fp32 or bf16 (template), W fp32 (converted to bf16 in staging), C bf16 or fp32.
// BM=BN=128, BK=64, 256 threads = 4 waves in 2x2, each wave owns 64x64 (4x4 MFMA frags).
// One 16x16x32 MFMA consumes K=32 (frag k = (lane>>4)*8 + j), so kk steps by 32.
// ---------------------------------------------------------------------------
template <bool A_BF16, bool OUT_F32>
__global__ __launch_bounds__(256) void gemm_nt_bias(
    const void* __restrict__ Ap, const float* __restrict__ W,
    const float* __restrict__ bias, void* __restrict__ Cp,
    int M, int N, int K)
{
    __shared__ bf16 As[128][72];  // BK=64 + pad 8 -> 144B row stride (2-way bank alias, free)
    __shared__ bf16 Bs[128][72];

    const int t = threadIdx.x;
    const int lane = t & 63;
    const int wid = t >> 6;
    const int wr = wid >> 1, wc = wid & 1;
    const int l15 = lane & 15, lg = lane >> 4;
    const int m0 = blockIdx.x * 128;
    const int n0 = blockIdx.y * 128;

    f32x4 acc[4][4] = {};

    for (int k0 = 0; k0 < K; k0 += 64) {
        // ---- stage A tile 128x64 ----
        if (A_BF16) {
            const bf16* A = (const bf16*)Ap;
#pragma unroll
            for (int i = 0; i < 4; ++i) {
                int chunk = t + i * 256;           // 1024 chunks of 8 bf16
                int row = chunk >> 3, c8 = (chunk & 7) * 8;
                *(bf16x8*)&As[row][c8] =
                    *(const bf16x8*)(A + (size_t)(m0 + row) * K + k0 + c8);
            }
        } else {
            const float* A = (const float*)Ap;
#pragma unroll
            for (int i = 0; i < 8; ++i) {
                int chunk = t + i * 256;           // 2048 chunks of 4 floats
                int row = chunk >> 4, c4 = (chunk & 15) * 4;
                f32x4 v = *(const f32x4*)(A + (size_t)(m0 + row) * K + k0 + c4);
                bf16x4 o;
#pragma unroll
                for (int j = 0; j < 4; ++j) o[j] = (bf16)v[j];
                *(bf16x4*)&As[row][c4] = o;
            }
        }
        // ---- stage B tile 128x64 (W rows are N, K-contiguous) ----
#pragma unroll
        for (int i = 0; i < 8; ++i) {
            int chunk = t + i * 256;
            int row = chunk >> 4, c4 = (chunk & 15) * 4;
            f32x4 v = *(const f32x4*)(W + (size_t)(n0 + row) * K + k0 + c4);
            bf16x4 o;
#pragma unroll
            for (int j = 0; j < 4; ++j) o[j] = (bf16)v[j];
            *(bf16x4*)&Bs[row][c4] = o;
        }
        __syncthreads();

#pragma unroll
        for (int kk = 0; kk < 64; kk += 32) {
            bf16x8 af[4], bfv[4];
#pragma unroll
            for (int mi = 0; mi < 4; ++mi)
                af[mi] = *(const bf16x8*)&As[wr * 64 + mi * 16 + l15][kk + lg * 8];
#pragma unroll
            for (int ni = 0; ni < 4; ++ni)
                bfv[ni] = *(const bf16x8*)&Bs[wc * 64 + ni * 16 + l15][kk + lg * 8];
#pragma unroll
            for (int mi = 0; mi < 4; ++mi)
#pragma unroll
                for (int ni = 0; ni < 4; ++ni)
                    acc[mi][ni] = MFMA_BF16(af[mi], bfv[ni], acc[mi][ni]);
        }
        __syncthreads();
    }

    // ---- epilogue: C/D layout col = lane&15, row = (lane>>4)*4 + reg ----
#pragma unroll
    for (int ni = 0; ni < 4; ++ni) {
        int col = n0 + wc * 64 + ni * 16 + l15;
        float bv = bias[col];
#pragma unroll
        for (int mi = 0; mi < 4; ++mi) {
#pragma unroll
            for (int r = 0; r < 4; ++r) {
                int row = m0 + wr * 64 + mi * 16 + lg * 4 + r;
                float val = acc[mi][ni][r] + bv;
                if (OUT_F32)
                    ((float*)Cp)[(size_t)row * N + col] = val;
                else
                    ((bf16*)Cp)[(size_t)row * N + col] = (bf16)val;
            }
        }
    }
}

// ---------------------------------------------------------------------------
// Flash attention forward. Grid: (S/128, B*H). 256 threads = 4 waves.
// Each wave owns 32 query rows. K/V tiles of 64 keys, online softmax.
// xq/xk/xv: bf16 [B,S,DA] (head h = cols h*64..h*64+63). out: bf16 [B,S,DA].
// ---------------------------------------------------------------------------
__global__ __launch_bounds__(256) void attn_kernel(
    const bf16* __restrict__ xq, const bf16* __restrict__ xk,
    const bf16* __restrict__ xv, const int* __restrict__ mask,
    bf16* __restrict__ out)
{
    __shared__ bf16 Qs[128][72];     // 64 + pad 8
    __shared__ bf16 Ks[64][72];
    __shared__ bf16 Vt[64][72];      // transposed: Vt[d][sk]
    __shared__ bf16 Ps[4][32][72];   // per-wave P tile

    const int t = threadIdx.x;
    const int lane = t & 63;
    const int wid = t >> 6;
    const int l15 = lane & 15, lg = lane >> 4;
    const int bh = blockIdx.y;
    const int b = bh >> 4, h = bh & 15;
    const int q0 = blockIdx.x * 128;
    const float scale = 0.125f;  // 1/sqrt(64)

    // stage Q tile 128x64
#pragma unroll
    for (int i = 0; i < 4; ++i) {
        int chunk = t + i * 256;
        int row = chunk >> 3, c8 = (chunk & 7) * 8;
        *(bf16x8*)&Qs[row][c8] =
            *(const bf16x8*)(xq + (size_t)(b * CS + q0 + row) * CDA + h * 64 + c8);
    }

    f32x4 accO[2][4] = {};
    float mrun[2][4], lrun[2][4];
#pragma unroll
    for (int mi = 0; mi < 2; ++mi)
#pragma unroll
        for (int r = 0; r < 4; ++r) { mrun[mi][r] = -__builtin_inff(); lrun[mi][r] = 0.f; }

    for (int kt = 0; kt < CS / 64; ++kt) {
        __syncthreads();  // previous iter's reads of Ks/Vt done (also covers Q staging)
        // stage K tile 64x64 (row-major, DH contiguous)
#pragma unroll
        for (int i = 0; i < 2; ++i) {
            int chunk = t + i * 256;
            int row = chunk >> 3, c8 = (chunk & 7) * 8;
            *(bf16x8*)&Ks[row][c8] =
                *(const bf16x8*)(xk + (size_t)(b * CS + kt * 64 + row) * CDA + h * 64 + c8);
        }
        // stage V tile transposed
#pragma unroll
        for (int i = 0; i < 2; ++i) {
            int chunk = t + i * 256;
            int row = chunk >> 3, c8 = (chunk & 7) * 8;
            bf16x8 v = *(const bf16x8*)(xv + (size_t)(b * CS + kt * 64 + row) * CDA + h * 64 + c8);
#pragma unroll
            for (int j = 0; j < 8; ++j) Vt[c8 + j][row] = v[j];
        }
        __syncthreads();

        // ---- QK^T: S[32 q rows][64 keys] per wave ----
        f32x4 s[2][4] = {};
#pragma unroll
        for (int kk = 0; kk < 64; kk += 32) {
            bf16x8 aq[2], bk[4];
#pragma unroll
            for (int mi = 0; mi < 2; ++mi)
                aq[mi] = *(const bf16x8*)&Qs[wid * 32 + mi * 16 + l15][kk + lg * 8];
#pragma unroll
            for (int ni = 0; ni < 4; ++ni)
                bk[ni] = *(const bf16x8*)&Ks[ni * 16 + l15][kk + lg * 8];
#pragma unroll
            for (int mi = 0; mi < 2; ++mi)
#pragma unroll
                for (int ni = 0; ni < 4; ++ni)
                    s[mi][ni] = MFMA_BF16(aq[mi], bk[ni], s[mi][ni]);
        }

        // ---- scale + mask ----
        int mk[4];
#pragma unroll
        for (int ni = 0; ni < 4; ++ni)
            mk[ni] = mask[b * CS + kt * 64 + ni * 16 + l15];
#pragma unroll
        for (int mi = 0; mi < 2; ++mi)
#pragma unroll
            for (int ni = 0; ni < 4; ++ni)
#pragma unroll
                for (int r = 0; r < 4; ++r) {
                    float v = s[mi][ni][r] * scale;
                    if (mk[ni] == 0) v = -3.0e38f;
                    s[mi][ni][r] = v;
                }

        // ---- row max (over 4 col-frags + 16 lanes) ----
        float fac[2][4], rsum[2][4];
#pragma unroll
        for (int mi = 0; mi < 2; ++mi)
#pragma unroll
            for (int r = 0; r < 4; ++r) {
                float m = fmaxf(fmaxf(s[mi][0][r], s[mi][1][r]),
                                fmaxf(s[mi][2][r], s[mi][3][r]));
                m = fmaxf(m, __shfl_xor(m, 1));
                m = fmaxf(m, __shfl_xor(m, 2));
                m = fmaxf(m, __shfl_xor(m, 4));
                m = fmaxf(m, __shfl_xor(m, 8));
                float mnew = fmaxf(mrun[mi][r], m);
                fac[mi][r] = __expf(mrun[mi][r] - mnew);
                mrun[mi][r] = mnew;
                rsum[mi][r] = 0.f;
            }

        // ---- P = exp(S - m), store bf16 to LDS, accumulate row sums ----
#pragma unroll
        for (int mi = 0; mi < 2; ++mi)
#pragma unroll
            for (int ni = 0; ni < 4; ++ni)
#pragma unroll
                for (int r = 0; r < 4; ++r) {
                    float p = __expf(s[mi][ni][r] - mrun[mi][r]);
                    rsum[mi][r] += p;
                    Ps[wid][mi * 16 + lg * 4 + r][ni * 16 + l15] = (bf16)p;
                }
#pragma unroll
        for (int mi = 0; mi < 2; ++mi)
#pragma unroll
            for (int r = 0; r < 4; ++r) {
                float rs = rsum[mi][r];
                rs += __shfl_xor(rs, 1);
                rs += __shfl_xor(rs, 2);
                rs += __shfl_xor(rs, 4);
                rs += __shfl_xor(rs, 8);
                lrun[mi][r] = lrun[mi][r] * fac[mi][r] + rs;
            }
#pragma unroll
        for (int mi = 0; mi < 2; ++mi)
#pragma unroll
            for (int di = 0; di < 4; ++di)
#pragma unroll
                for (int r = 0; r < 4; ++r)
                    accO[mi][di][r] *= fac[mi][r];

        // ---- PV: O += P * V ----
#pragma unroll
        for (int kks = 0; kks < 2; ++kks) {
            bf16x8 ap[2], bv[4];
#pragma unroll
            for (int mi = 0; mi < 2; ++mi)
                ap[mi] = *(const bf16x8*)&Ps[wid][mi * 16 + l15][kks * 32 + lg * 8];
#pragma unroll
            for (int di = 0; di < 4; ++di)
                bv[di] = *(const bf16x8*)&Vt[di * 16 + l15][kks * 32 + lg * 8];
#pragma unroll
            for (int mi = 0; mi < 2; ++mi)
#pragma unroll
                for (int di = 0; di < 4; ++di)
                    accO[mi][di] = MFMA_BF16(ap[mi], bv[di], accO[mi][di]);
        }
    }

    // ---- epilogue: O / l ----
#pragma unroll
    for (int mi = 0; mi < 2; ++mi)
#pragma unroll
        for (int r = 0; r < 4; ++r) {
            float inv = 1.f / lrun[mi][r];
#pragma unroll
            for (int di = 0; di < 4; ++di) {
                int row = q0 + wid * 32 + mi * 16 + lg * 4 + r;
                int col = h * 64 + di * 16 + l15;
                out[(size_t)(b * CS + row) * CDA + col] = (bf16)(accO[mi][di][r] * inv);
            }
        }
}

// ---------------------------------------------------------------------------
extern "C" void kernel_launch(void* const* d_in, const int* in_sizes, int n_in,
                              void* d_out, int out_size, void* d_ws, size_t ws_size,
                              hipStream_t stream)
{
    const float* q   = (const float*)d_in[0];
    const float* k   = (const float*)d_in[1];
    const float* v   = (const float*)d_in[2];
    const int*   msk = (const int*)d_in[3];
    const float* w_q = (const float*)d_in[4];
    const float* b_q = (const float*)d_in[5];
    const float* w_k = (const float*)d_in[6];
    const float* b_k = (const float*)d_in[7];
    const float* w_v = (const float*)d_in[8];
    const float* b_v = (const float*)d_in[9];
    const float* w_o = (const float*)d_in[10];
    const float* b_o = (const float*)d_in[11];

    bf16* xq = (bf16*)d_ws;
    bf16* xk = xq + (size_t)CM * CDA;
    bf16* xv = xk + (size_t)CM * CDA;
    bf16* at = xv + (size_t)CM * CDA;

    dim3 gp(CM / 128, CDA / 128);
    gemm_nt_bias<false, false><<<gp, 256, 0, stream>>>((const void*)q, w_q, b_q, (void*)xq, CM, CDA, CD);
    gemm_nt_bias<false, false><<<gp, 256, 0, stream>>>((const void*)k, w_k, b_k, (void*)xk, CM, CDA, CD);
    gemm_nt_bias<false, false><<<gp, 256, 0, stream>>>((const void*)v, w_v, b_v, (void*)xv, CM, CDA, CD);

    attn_kernel<<<dim3(CS / 128, CB * CH), 256, 0, stream>>>(xq, xk, xv, msk, at);

    gemm_nt_bias<true, true><<<dim3(CM / 128, CD / 128), 256, 0, stream>>>(
        (const void*)at, w_o, b_o, d_out, CM, CD, CDA);
}